// Round 19
// baseline (323.123 us; speedup 1.0000x reference)
//
#include <hip/hip_runtime.h>

#define NN 100000   // nodes
#define NE 1600000  // edges
#define DD 128      // feature dim
#define NL 3        // layers
#define NG 64       // graphs
#define EPSBN 1e-5f
#define NBUCK 196               // ceil(NN/512) buckets of 512 nodes
#define NAGG (NN / 16)          // 6250 agg blocks (16 nodes each)
#define NSCAT 256               // scatter blocks (NE = 256*6250)

typedef __attribute__((ext_vector_type(8))) short short8v;   // 8 bf16 (4 VGPR)
typedef __attribute__((ext_vector_type(4))) float float4v;   // MFMA C/D
typedef __attribute__((ext_vector_type(2))) float float2v;   // fp8 cvt result

// ---- fp32 atomic add (HW global_atomic_add_f32, no CAS loop) ----
__device__ inline void atomAddF(float* p, float v) {
#if defined(__AMDGCN__)
    unsafeAtomicAdd(p, v);
#else
    atomicAdd(p, v);
#endif
}

// ---- fp32 -> bf16 round-to-nearest-even ----
__device__ inline ushort f2bf(float f) {
    uint u = __float_as_uint(f);
    uint r = ((u >> 16) & 1u) + 0x7fffu;
    return (ushort)((u + r) >> 16);
}

// ---- fp32 -> fp8 e4m3 (OCP, HW convert) ----
__device__ inline uint f2fp8(float f) {
    return (uint)__builtin_amdgcn_cvt_pk_fp8_f32(f, f, 0, false) & 0xffu;
}

// ---- accumulate 8 fp8 lanes (packed in uint2) scaled by wgt into acc[8] ----
__device__ inline void accf8(float (&acc)[8], uint2 g, float wgt) {
    float2v p0 = __builtin_amdgcn_cvt_pk_f32_fp8(g.x, false);
    float2v p1 = __builtin_amdgcn_cvt_pk_f32_fp8(g.x, true);
    float2v p2 = __builtin_amdgcn_cvt_pk_f32_fp8(g.y, false);
    float2v p3 = __builtin_amdgcn_cvt_pk_f32_fp8(g.y, true);
    acc[0] = fmaf(wgt, p0[0], acc[0]);
    acc[1] = fmaf(wgt, p0[1], acc[1]);
    acc[2] = fmaf(wgt, p1[0], acc[2]);
    acc[3] = fmaf(wgt, p1[1], acc[3]);
    acc[4] = fmaf(wgt, p2[0], acc[4]);
    acc[5] = fmaf(wgt, p2[1], acc[5]);
    acc[6] = fmaf(wgt, p3[0], acc[6]);
    acc[7] = fmaf(wgt, p3[1], acc[7]);
}

// ---------------- bcnt + init fused ----------------
__global__ __launch_bounds__(256) void k_bcnt2(const int* __restrict__ ei,
                                               const float* __restrict__ W,
                                               ushort* __restrict__ Wt,
                                               float* __restrict__ out,
                                               float* __restrict__ stats,
                                               int* __restrict__ hist) {
    __shared__ int lh[NBUCK];
    const int tid = threadIdx.x;
    if (tid < NBUCK) lh[tid] = 0;
    __syncthreads();

    // init work interleaved (index space 58112 < 65536)
    int gi = blockIdx.x * 256 + tid;
    if (gi < NL * DD * DD) {
        int l = gi >> 14, r = gi & 16383;
        int k = r >> 7, n = r & 127;
        Wt[(size_t)l * DD * DD + n * DD + k] = f2bf(W[gi]);
    } else {
        int j = gi - NL * DD * DD;
        if (j < NG * DD) out[j] = 0.f;
        else if (j - NG * DD < 768) stats[j - NG * DD] = 0.f;
    }

    const int e0 = blockIdx.x * 6250, e1 = e0 + 6250;
    for (int e = e0 + tid; e < e1; e += 256)
        atomicAdd(&lh[ei[NE + e] >> 9], 1);
    __syncthreads();
    if (tid < NBUCK) hist[blockIdx.x * NBUCK + tid] = lh[tid];
}

// ---------------- scan: boff (exclusive) + per-block prefix matrix --------
__global__ __launch_bounds__(256) void k_bscan2(const int* __restrict__ hist,
                                                int* __restrict__ prefix,
                                                int* __restrict__ boff) {
    __shared__ int s[256];
    int t = threadIdx.x;
    int cum = 0;
    if (t < NBUCK) {
        for (int blk = 0; blk < NSCAT; ++blk) {
            int v = hist[blk * NBUCK + t];
            prefix[blk * NBUCK + t] = cum;
            cum += v;
        }
    }
    s[t] = (t < NBUCK) ? cum : 0;
    __syncthreads();
    int v = s[t];
    for (int off = 1; off < 256; off <<= 1) {
        int add = (t >= off) ? s[t - off] : 0;
        __syncthreads();
        s[t] += add;
        __syncthreads();
    }
    if (t < NBUCK) boff[t] = s[t] - v;  // exclusive
    if (t == NBUCK - 1) boff[NBUCK] = s[t];  // = NE
}

// ---------------- scatter (single pass, no global atomics) ----------------
__global__ __launch_bounds__(256) void k_bscatter2(const int* __restrict__ ei,
                                                   const float* __restrict__ ew,
                                                   const int* __restrict__ prefix,
                                                   const int* __restrict__ boff,
                                                   int2* __restrict__ srcw) {
    __shared__ int base[NBUCK], cur[NBUCK];
    const int tid = threadIdx.x;
    if (tid < NBUCK) {
        base[tid] = boff[tid] + prefix[blockIdx.x * NBUCK + tid];
        cur[tid] = 0;
    }
    __syncthreads();
    const int e0 = blockIdx.x * 6250, e1 = e0 + 6250;
    for (int e = e0 + tid; e < e1; e += 256) {
        int d = ei[NE + e];
        int b = d >> 9;
        int p = base[b] + atomicAdd(&cur[b], 1);
        int2 sw;
        sw.x = ei[e] | ((d & 511) << 17);
        sw.y = __float_as_int(ew[e]);
        srcw[p] = sw;
    }
}

// ---------------- per-bucket counting sort -> CSR + row_off + dinv --------
__global__ __launch_bounds__(256) void k_bsort(const int2* __restrict__ srcw,
                                               const int* __restrict__ boff,
                                               int* __restrict__ row_off,
                                               int2* __restrict__ csr,
                                               float* __restrict__ dinv) {
    __shared__ int h0[512], h1[512], exc[512], cur[512];
    __shared__ float degacc[512];
    const int tid = threadIdx.x;
    const int b = blockIdx.x;
    const int p0 = boff[b], p1 = boff[b + 1];
    const int nbn = min(512, NN - (b << 9));

    for (int i = tid; i < 512; i += 256) {
        h0[i] = 0;
        degacc[i] = 0.f;
    }
    __syncthreads();
    for (int p = p0 + tid; p < p1; p += 256)
        atomicAdd(&h0[(srcw[p].x >> 17) & 511], 1);
    __syncthreads();

    int* sA = h0;
    int* sB = h1;
    for (int off = 1; off < 512; off <<= 1) {
        for (int i = tid; i < 512; i += 256) {
            int v = sA[i];
            if (i >= off) v += sA[i - off];
            sB[i] = v;
        }
        __syncthreads();
        int* tp = sA; sA = sB; sB = tp;
    }
    for (int i = tid; i < 512; i += 256) {
        exc[i] = (i == 0) ? 0 : sA[i - 1];
        cur[i] = 0;
    }
    __syncthreads();

    for (int n = tid; n < nbn; n += 256)
        row_off[(b << 9) + n] = p0 + exc[n];
    if (b == NBUCK - 1 && tid == 0) row_off[NN] = NE;

    for (int p = p0 + tid; p < p1; p += 256) {
        int2 sw = srcw[p];
        int dl = (sw.x >> 17) & 511;
        int q = p0 + exc[dl] + atomicAdd(&cur[dl], 1);
        int2 outv;
        outv.x = sw.x & 0x1FFFF;   // clean src
        outv.y = sw.y;             // raw ew (H is pre-scaled by dinv[src])
        csr[q] = outv;
        atomicAdd(&degacc[dl], __int_as_float(sw.y));
    }
    __syncthreads();
    for (int n = tid; n < nbn; n += 256)
        dinv[(b << 9) + n] = rsqrtf(1.0f + degacc[n]);  // 1 = self-loop
}

// ---------------- MFMA GEMM: H' = dinv * (act(X) @ W), fp8 e4m3 ------------
// 64 rows x 128 cols per block, 4 waves; A-fragments direct from global;
// only W in LDS (33KB) -> 4 blocks/CU. Epilogue scales row by dinv[row]
// so the aggregation needs no dinv[src] gather.
__global__ __launch_bounds__(256, 4) void k_gemm5(const float* __restrict__ X,
                                                  const ushort* __restrict__ Xb,
                                                  const ushort* __restrict__ Wt,
                                                  const float* __restrict__ stats,
                                                  const float* __restrict__ gamma,
                                                  const float* __restrict__ beta,
                                                  const float* __restrict__ dinv,
                                                  int applyBN,
                                                  unsigned char* __restrict__ H) {
    __shared__ ushort ws[128 * 128];   // 32KB [n][k] bf16, swizzled
    __shared__ float scs[DD], shs[DD];
    const int tid = threadIdx.x;

    for (int c = tid; c < 2048; c += 256) {
        int n = c >> 4, k8 = (c & 15) * 8;
        uint4 w = *(const uint4*)&Wt[n * DD + k8];
        int idx = n * 128 + (((k8 * 2) ^ ((n & 7) << 4)) >> 1);
        *(uint4*)&ws[idx] = w;
    }
    if (applyBN && tid < DD) {
        float mu = stats[tid] * (1.0f / NN);
        float var = stats[DD + tid] * (1.0f / NN) - mu * mu;
        float inv = rsqrtf(var + EPSBN);
        float s = gamma[tid] * inv;
        scs[tid] = s;
        shs[tid] = beta[tid] - mu * s;
    }
    __syncthreads();

    const int wid = tid >> 6, lane = tid & 63;
    const int lrow = lane & 15, lk = lane >> 4;
    const int gr_a = blockIdx.x * 64 + wid * 16 + lrow;  // A row for this lane

    float4v acc[8];
#pragma unroll
    for (int i = 0; i < 8; ++i) acc[i] = (float4v){0.f, 0.f, 0.f, 0.f};

#pragma unroll
    for (int ks = 0; ks < 4; ++ks) {
        const int k8 = ks * 32 + lk * 8;   // this lane's 8 k-elements
        float v[8];
        if (applyBN) {
            uint4 g = (gr_a < NN) ? *(const uint4*)&Xb[(size_t)gr_a * DD + k8]
                                  : make_uint4(0u, 0u, 0u, 0u);
            v[0] = __uint_as_float(g.x << 16);
            v[1] = __uint_as_float(g.x & 0xffff0000u);
            v[2] = __uint_as_float(g.y << 16);
            v[3] = __uint_as_float(g.y & 0xffff0000u);
            v[4] = __uint_as_float(g.z << 16);
            v[5] = __uint_as_float(g.z & 0xffff0000u);
            v[6] = __uint_as_float(g.w << 16);
            v[7] = __uint_as_float(g.w & 0xffff0000u);
#pragma unroll
            for (int i = 0; i < 8; ++i)
                v[i] = fmaxf(fmaf(v[i], scs[k8 + i], shs[k8 + i]), 0.f);
        } else {
            if (gr_a < NN) {
                float4 a0 = *(const float4*)&X[(size_t)gr_a * DD + k8];
                float4 a1 = *(const float4*)&X[(size_t)gr_a * DD + k8 + 4];
                v[0] = a0.x; v[1] = a0.y; v[2] = a0.z; v[3] = a0.w;
                v[4] = a1.x; v[5] = a1.y; v[6] = a1.z; v[7] = a1.w;
            } else {
#pragma unroll
                for (int i = 0; i < 8; ++i) v[i] = 0.f;
            }
        }
        uint4 ap;
        ap.x = (uint)f2bf(v[0]) | ((uint)f2bf(v[1]) << 16);
        ap.y = (uint)f2bf(v[2]) | ((uint)f2bf(v[3]) << 16);
        ap.z = (uint)f2bf(v[4]) | ((uint)f2bf(v[5]) << 16);
        ap.w = (uint)f2bf(v[6]) | ((uint)f2bf(v[7]) << 16);
        short8v a = *(short8v*)&ap;

        const int kbyte = ks * 64 + lk * 16;
#pragma unroll
        for (int ng = 0; ng < 8; ++ng) {
            int n = ng * 16 + lrow;
            short8v b = *(const short8v*)&ws[n * 128 + ((kbyte ^ ((n & 7) << 4)) >> 1)];
            acc[ng] = __builtin_amdgcn_mfma_f32_16x16x32_bf16(a, b, acc[ng], 0, 0, 0);
        }
    }

    // C/D layout: col = lane&15, row = (lane>>4)*4 + reg  [m89]
    const int rbase = blockIdx.x * 64 + wid * 16 + lk * 4;
    float dvr[4];
#pragma unroll
    for (int j = 0; j < 4; ++j)
        dvr[j] = (rbase + j < NN) ? dinv[rbase + j] : 0.f;
#pragma unroll
    for (int ng = 0; ng < 8; ++ng) {
        int col = ng * 16 + lrow;
#pragma unroll
        for (int j = 0; j < 4; ++j) {
            int gr = rbase + j;
            if (gr < NN)
                H[(size_t)gr * DD + col] = (unsigned char)f2fp8(dvr[j] * acc[ng][j]);
        }
    }
}

// ---------------- aggregation + fused BN stats ----------------------------
// H is pre-scaled by dinv[row]: edge weight = raw ew; self-loop seed = 1.0;
// final *dv completes dinv[dst]*ew*dinv[src] and dv^2 for the self loop.
__global__ __launch_bounds__(256) void k_agg3(const int2* __restrict__ csr,
                                              const int* __restrict__ row_off,
                                              const float* __restrict__ dinv,
                                              const unsigned char* __restrict__ H,
                                              ushort* __restrict__ Ab,
                                              float* __restrict__ partial) {
    __shared__ float sbv[16][128];
    __shared__ float sbq[16][128];
    const int tid = threadIdx.x;
    int node = blockIdx.x * 16 + (tid >> 4);
    int h = tid & 15;
    int beg = row_off[node], end = row_off[node + 1];
    float dv = dinv[node];
    size_t cb = (size_t)node * DD + h * 8;   // byte index
    float acc[8] = {0.f, 0.f, 0.f, 0.f, 0.f, 0.f, 0.f, 0.f};
    {
        uint2 v = *(const uint2*)&H[cb];
        accf8(acc, v, 1.0f);  // H'[node] = dv*H[node]; final *dv gives dv^2*H
    }

    int j = beg;
    for (; j + 8 <= end; j += 8) {
        int2 e0 = csr[j], e1 = csr[j + 1], e2 = csr[j + 2], e3 = csr[j + 3];
        int2 e4 = csr[j + 4], e5 = csr[j + 5], e6 = csr[j + 6], e7 = csr[j + 7];
        uint2 g0 = *(const uint2*)&H[(size_t)e0.x * DD + h * 8];
        uint2 g1 = *(const uint2*)&H[(size_t)e1.x * DD + h * 8];
        uint2 g2 = *(const uint2*)&H[(size_t)e2.x * DD + h * 8];
        uint2 g3 = *(const uint2*)&H[(size_t)e3.x * DD + h * 8];
        uint2 g4 = *(const uint2*)&H[(size_t)e4.x * DD + h * 8];
        uint2 g5 = *(const uint2*)&H[(size_t)e5.x * DD + h * 8];
        uint2 g6 = *(const uint2*)&H[(size_t)e6.x * DD + h * 8];
        uint2 g7 = *(const uint2*)&H[(size_t)e7.x * DD + h * 8];
        accf8(acc, g0, __int_as_float(e0.y));
        accf8(acc, g1, __int_as_float(e1.y));
        accf8(acc, g2, __int_as_float(e2.y));
        accf8(acc, g3, __int_as_float(e3.y));
        accf8(acc, g4, __int_as_float(e4.y));
        accf8(acc, g5, __int_as_float(e5.y));
        accf8(acc, g6, __int_as_float(e6.y));
        accf8(acc, g7, __int_as_float(e7.y));
    }
    for (; j + 4 <= end; j += 4) {
        int2 e0 = csr[j], e1 = csr[j + 1], e2 = csr[j + 2], e3 = csr[j + 3];
        uint2 g0 = *(const uint2*)&H[(size_t)e0.x * DD + h * 8];
        uint2 g1 = *(const uint2*)&H[(size_t)e1.x * DD + h * 8];
        uint2 g2 = *(const uint2*)&H[(size_t)e2.x * DD + h * 8];
        uint2 g3 = *(const uint2*)&H[(size_t)e3.x * DD + h * 8];
        accf8(acc, g0, __int_as_float(e0.y));
        accf8(acc, g1, __int_as_float(e1.y));
        accf8(acc, g2, __int_as_float(e2.y));
        accf8(acc, g3, __int_as_float(e3.y));
    }
    for (; j < end; ++j) {
        int2 e = csr[j];
        uint2 g = *(const uint2*)&H[(size_t)e.x * DD + h * 8];
        accf8(acc, g, __int_as_float(e.y));
    }

#pragma unroll
    for (int i = 0; i < 8; ++i) acc[i] *= dv;

    uint4 st;
    st.x = (uint)f2bf(acc[0]) | ((uint)f2bf(acc[1]) << 16);
    st.y = (uint)f2bf(acc[2]) | ((uint)f2bf(acc[3]) << 16);
    st.z = (uint)f2bf(acc[4]) | ((uint)f2bf(acc[5]) << 16);
    st.w = (uint)f2bf(acc[6]) | ((uint)f2bf(acc[7]) << 16);
    *(uint4*)&Ab[cb] = st;

    int n = tid >> 4, c0 = h * 8;
#pragma unroll
    for (int i = 0; i < 8; ++i) {
        float a = acc[i];
        sbv[n][c0 + i] = a;
        sbq[n][c0 + i] = a * a;
    }
    __syncthreads();
    float s = 0.f;
    if (tid < 128) {
#pragma unroll
        for (int k = 0; k < 16; ++k) s += sbv[k][tid];
    } else {
        int c = tid - 128;
#pragma unroll
        for (int k = 0; k < 16; ++k) s += sbq[k][c];
    }
    partial[(size_t)blockIdx.x * 256 + tid] = s;
}

// ---------------- reduce partials -> stats (low-contention atomics) -------
__global__ __launch_bounds__(256) void k_bn_red(const float* __restrict__ partial,
                                                float* __restrict__ stats) {
    int r0 = blockIdx.x * 25;
    int r1 = min(r0 + 25, NAGG);
    int t = threadIdx.x;
    float s = 0.f;
    for (int r = r0; r < r1; ++r) s += partial[(size_t)r * 256 + t];
    atomAddF(&stats[t], s);
}

// ---------------- pooling (fused final BN+ReLU), vectorized ---------------
__global__ __launch_bounds__(256) void k_pool(const ushort* __restrict__ Ab,
                                              const int* __restrict__ batch,
                                              const float* __restrict__ stats,
                                              const float* __restrict__ gamma,
                                              const float* __restrict__ beta,
                                              float* __restrict__ out) {
    __shared__ int bsh[512];
    __shared__ float scs[DD], shs[DD];
    const int tid = threadIdx.x;
    const int lane = tid & 15, rg = tid >> 4;
    const int c0 = lane * 8;
    const int v0 = blockIdx.x * 512;
    const int v1 = min(v0 + 512, NN);
    for (int i = tid; i < v1 - v0; i += 256) bsh[i] = batch[v0 + i];
    if (tid < DD) {
        float mu = stats[tid] * (1.0f / NN);
        float var = stats[DD + tid] * (1.0f / NN) - mu * mu;
        float inv = rsqrtf(var + EPSBN);
        float s = gamma[tid] * inv;
        scs[tid] = s;
        shs[tid] = beta[tid] - mu * s;
    }
    __syncthreads();

    float s[8], t[8];
#pragma unroll
    for (int i = 0; i < 8; ++i) {
        s[i] = scs[c0 + i];
        t[i] = shs[c0 + i];
    }
    float acc[8] = {0.f, 0.f, 0.f, 0.f, 0.f, 0.f, 0.f, 0.f};
    int g = -1;
    for (int v = v0 + rg; v < v1; v += 16) {
        int bg = bsh[v - v0];
        if (bg != g) {
            if (g >= 0) {
                float* op = &out[(size_t)g * DD + c0];
#pragma unroll
                for (int i = 0; i < 8; ++i) atomAddF(op + i, acc[i]);
            }
            g = bg;
#pragma unroll
            for (int i = 0; i < 8; ++i) acc[i] = 0.f;
        }
        uint4 a = *(const uint4*)&Ab[(size_t)v * DD + c0];
        float x0 = __uint_as_float(a.x << 16);
        float x1 = __uint_as_float(a.x & 0xffff0000u);
        float x2 = __uint_as_float(a.y << 16);
        float x3 = __uint_as_float(a.y & 0xffff0000u);
        float x4 = __uint_as_float(a.z << 16);
        float x5 = __uint_as_float(a.z & 0xffff0000u);
        float x6 = __uint_as_float(a.w << 16);
        float x7 = __uint_as_float(a.w & 0xffff0000u);
        acc[0] += fmaxf(fmaf(x0, s[0], t[0]), 0.f);
        acc[1] += fmaxf(fmaf(x1, s[1], t[1]), 0.f);
        acc[2] += fmaxf(fmaf(x2, s[2], t[2]), 0.f);
        acc[3] += fmaxf(fmaf(x3, s[3], t[3]), 0.f);
        acc[4] += fmaxf(fmaf(x4, s[4], t[4]), 0.f);
        acc[5] += fmaxf(fmaf(x5, s[5], t[5]), 0.f);
        acc[6] += fmaxf(fmaf(x6, s[6], t[6]), 0.f);
        acc[7] += fmaxf(fmaf(x7, s[7], t[7]), 0.f);
    }
    if (g >= 0) {
        float* op = &out[(size_t)g * DD + c0];
#pragma unroll
        for (int i = 0; i < 8; ++i) atomAddF(op + i, acc[i]);
    }
}

extern "C" void kernel_launch(void* const* d_in, const int* in_sizes, int n_in,
                              void* d_out, int out_size, void* d_ws, size_t ws_size,
                              hipStream_t stream) {
    const float* x     = (const float*)d_in[0];
    const int*   ei    = (const int*)d_in[1];
    const float* ew    = (const float*)d_in[2];
    const int*   batch = (const int*)d_in[3];
    const float* W     = (const float*)d_in[4];
    // d_in[5] = b — cancels exactly in training-mode BatchNorm, unused
    const float* gamma = (const float*)d_in[6];
    const float* beta  = (const float*)d_in[7];
    float* out = (float*)d_out;

    float* wsp   = (float*)d_ws;
    float* dinv  = wsp;                            // N
    float* stats = dinv + NN;                      // 768
    ushort* Wt   = (ushort*)(stats + 768);         // 3 x D x D bf16
    unsigned char* H = (unsigned char*)(Wt + (size_t)NL * DD * DD);  // N*D fp8
    ushort* Ab   = (ushort*)(H + (size_t)NN * DD); // N*D bf16
    int2*  srcw  = (int2*)(Ab + (size_t)NN * DD);  // E packed records
    float* partial = (float*)(srcw + NE);          // NAGG x 256
    int*   row_off = (int*)(partial + (size_t)NAGG * 256);  // N+4
    int*   hist  = row_off + NN + 4;               // NSCAT x NBUCK
    int*   prefix = hist + NSCAT * NBUCK;          // NSCAT x NBUCK
    int*   boff  = prefix + NSCAT * NBUCK;         // NBUCK+4 (padded)
    int2*  csr   = (int2*)(boff + NBUCK + 4);      // E * 8B
    // total ≈ 71 MiB

    // build chain: per-block histograms (+init) -> scan -> scatter -> sort
    k_bcnt2<<<NSCAT, 256, 0, stream>>>(ei, W, Wt, out, stats, hist);
    k_bscan2<<<1, 256, 0, stream>>>(hist, prefix, boff);
    k_bscatter2<<<NSCAT, 256, 0, stream>>>(ei, ew, prefix, boff, srcw);
    k_bsort<<<NBUCK, 256, 0, stream>>>(srcw, boff, row_off, csr, dinv);

    for (int l = 0; l < NL; ++l) {
        const float* st_prev = stats + (l - 1) * 256;   // unused when l==0
        const float* ga_prev = gamma + (size_t)(l > 0 ? l - 1 : 0) * DD;
        const float* be_prev = beta + (size_t)(l > 0 ? l - 1 : 0) * DD;
        k_gemm5<<<(NN + 63) / 64, 256, 0, stream>>>(
            x, Ab, Wt + (size_t)l * DD * DD, l > 0 ? st_prev : stats,
            ga_prev, be_prev, dinv, l > 0 ? 1 : 0, H);
        k_agg3<<<NAGG, 256, 0, stream>>>(csr, row_off, dinv, H, Ab, partial);
        k_bn_red<<<(NAGG + 24) / 25, 256, 0, stream>>>(partial, stats + l * 256);
    }

    k_pool<<<NBUCK, 256, 0, stream>>>(Ab, batch, stats + 2 * 256,
                                      gamma + 2 * DD, beta + 2 * DD, out);
}

// Round 20
// 308.565 us; speedup vs baseline: 1.0472x; 1.0472x over previous
//
#include <hip/hip_runtime.h>

#define NN 100000   // nodes
#define NE 1600000  // edges
#define DD 128      // feature dim
#define NL 3        // layers
#define NG 64       // graphs
#define EPSBN 1e-5f
#define NBUCK 196               // ceil(NN/512) buckets of 512 nodes
#define NAGG (NN / 16)          // 6250 agg blocks (16 nodes each)
#define NSCAT 256               // scatter blocks (NE = 256*6250)

typedef __attribute__((ext_vector_type(8))) short short8v;   // 8 bf16 (4 VGPR)
typedef __attribute__((ext_vector_type(4))) float float4v;   // MFMA C/D
typedef __attribute__((ext_vector_type(2))) float float2v;   // fp8 cvt result

// ---- fp32 atomic add (HW global_atomic_add_f32, no CAS loop) ----
__device__ inline void atomAddF(float* p, float v) {
#if defined(__AMDGCN__)
    unsafeAtomicAdd(p, v);
#else
    atomicAdd(p, v);
#endif
}

// ---- fp32 -> bf16 round-to-nearest-even ----
__device__ inline ushort f2bf(float f) {
    uint u = __float_as_uint(f);
    uint r = ((u >> 16) & 1u) + 0x7fffu;
    return (ushort)((u + r) >> 16);
}

// ---- fp32 -> fp8 e4m3 (OCP, HW convert) ----
__device__ inline uint f2fp8(float f) {
    return (uint)__builtin_amdgcn_cvt_pk_fp8_f32(f, f, 0, false) & 0xffu;
}

// ---- accumulate 8 fp8 lanes (packed in uint2) scaled by wgt into acc[8] ----
__device__ inline void accf8(float (&acc)[8], uint2 g, float wgt) {
    float2v p0 = __builtin_amdgcn_cvt_pk_f32_fp8(g.x, false);
    float2v p1 = __builtin_amdgcn_cvt_pk_f32_fp8(g.x, true);
    float2v p2 = __builtin_amdgcn_cvt_pk_f32_fp8(g.y, false);
    float2v p3 = __builtin_amdgcn_cvt_pk_f32_fp8(g.y, true);
    acc[0] = fmaf(wgt, p0[0], acc[0]);
    acc[1] = fmaf(wgt, p0[1], acc[1]);
    acc[2] = fmaf(wgt, p1[0], acc[2]);
    acc[3] = fmaf(wgt, p1[1], acc[3]);
    acc[4] = fmaf(wgt, p2[0], acc[4]);
    acc[5] = fmaf(wgt, p2[1], acc[5]);
    acc[6] = fmaf(wgt, p3[0], acc[6]);
    acc[7] = fmaf(wgt, p3[1], acc[7]);
}

// ---------------- bcnt + init fused ----------------
__global__ __launch_bounds__(256) void k_bcnt2(const int* __restrict__ ei,
                                               const float* __restrict__ W,
                                               ushort* __restrict__ Wt,
                                               float* __restrict__ out,
                                               float* __restrict__ stats,
                                               int* __restrict__ hist) {
    __shared__ int lh[NBUCK];
    const int tid = threadIdx.x;
    if (tid < NBUCK) lh[tid] = 0;
    __syncthreads();

    // init work interleaved (index space 58112 < 65536)
    int gi = blockIdx.x * 256 + tid;
    if (gi < NL * DD * DD) {
        int l = gi >> 14, r = gi & 16383;
        int k = r >> 7, n = r & 127;
        Wt[(size_t)l * DD * DD + n * DD + k] = f2bf(W[gi]);
    } else {
        int j = gi - NL * DD * DD;
        if (j < NG * DD) out[j] = 0.f;
        else if (j - NG * DD < 768) stats[j - NG * DD] = 0.f;
    }

    const int e0 = blockIdx.x * 6250, e1 = e0 + 6250;
    for (int e = e0 + tid; e < e1; e += 256)
        atomicAdd(&lh[ei[NE + e] >> 9], 1);
    __syncthreads();
    if (tid < NBUCK) hist[blockIdx.x * NBUCK + tid] = lh[tid];
}

// ---------------- scan: boff (exclusive) + per-block prefix matrix --------
__global__ __launch_bounds__(256) void k_bscan2(const int* __restrict__ hist,
                                                int* __restrict__ prefix,
                                                int* __restrict__ boff) {
    __shared__ int s[256];
    int t = threadIdx.x;
    int cum = 0;
    if (t < NBUCK) {
        for (int blk = 0; blk < NSCAT; ++blk) {
            int v = hist[blk * NBUCK + t];
            prefix[blk * NBUCK + t] = cum;
            cum += v;
        }
    }
    s[t] = (t < NBUCK) ? cum : 0;
    __syncthreads();
    int v = s[t];
    for (int off = 1; off < 256; off <<= 1) {
        int add = (t >= off) ? s[t - off] : 0;
        __syncthreads();
        s[t] += add;
        __syncthreads();
    }
    if (t < NBUCK) boff[t] = s[t] - v;  // exclusive
    if (t == NBUCK - 1) boff[NBUCK] = s[t];  // = NE
}

// ---------------- scatter (single pass, no global atomics) ----------------
__global__ __launch_bounds__(256) void k_bscatter2(const int* __restrict__ ei,
                                                   const float* __restrict__ ew,
                                                   const int* __restrict__ prefix,
                                                   const int* __restrict__ boff,
                                                   int2* __restrict__ srcw) {
    __shared__ int base[NBUCK], cur[NBUCK];
    const int tid = threadIdx.x;
    if (tid < NBUCK) {
        base[tid] = boff[tid] + prefix[blockIdx.x * NBUCK + tid];
        cur[tid] = 0;
    }
    __syncthreads();
    const int e0 = blockIdx.x * 6250, e1 = e0 + 6250;
    for (int e = e0 + tid; e < e1; e += 256) {
        int d = ei[NE + e];
        int b = d >> 9;
        int p = base[b] + atomicAdd(&cur[b], 1);
        int2 sw;
        sw.x = ei[e] | ((d & 511) << 17);
        sw.y = __float_as_int(ew[e]);
        srcw[p] = sw;
    }
}

// ---------------- per-bucket counting sort -> CSR + row_off + dinv --------
__global__ __launch_bounds__(256) void k_bsort(const int2* __restrict__ srcw,
                                               const int* __restrict__ boff,
                                               int* __restrict__ row_off,
                                               int2* __restrict__ csr,
                                               float* __restrict__ dinv) {
    __shared__ int h0[512], h1[512], exc[512], cur[512];
    __shared__ float degacc[512];
    const int tid = threadIdx.x;
    const int b = blockIdx.x;
    const int p0 = boff[b], p1 = boff[b + 1];
    const int nbn = min(512, NN - (b << 9));

    for (int i = tid; i < 512; i += 256) {
        h0[i] = 0;
        degacc[i] = 0.f;
    }
    __syncthreads();
    for (int p = p0 + tid; p < p1; p += 256)
        atomicAdd(&h0[(srcw[p].x >> 17) & 511], 1);
    __syncthreads();

    int* sA = h0;
    int* sB = h1;
    for (int off = 1; off < 512; off <<= 1) {
        for (int i = tid; i < 512; i += 256) {
            int v = sA[i];
            if (i >= off) v += sA[i - off];
            sB[i] = v;
        }
        __syncthreads();
        int* tp = sA; sA = sB; sB = tp;
    }
    for (int i = tid; i < 512; i += 256) {
        exc[i] = (i == 0) ? 0 : sA[i - 1];
        cur[i] = 0;
    }
    __syncthreads();

    for (int n = tid; n < nbn; n += 256)
        row_off[(b << 9) + n] = p0 + exc[n];
    if (b == NBUCK - 1 && tid == 0) row_off[NN] = NE;

    for (int p = p0 + tid; p < p1; p += 256) {
        int2 sw = srcw[p];
        int dl = (sw.x >> 17) & 511;
        int q = p0 + exc[dl] + atomicAdd(&cur[dl], 1);
        int2 outv;
        outv.x = sw.x & 0x1FFFF;   // clean src
        outv.y = sw.y;             // raw ew (H is pre-scaled by dinv[src])
        csr[q] = outv;
        atomicAdd(&degacc[dl], __int_as_float(sw.y));
    }
    __syncthreads();
    for (int n = tid; n < nbn; n += 256)
        dinv[(b << 9) + n] = rsqrtf(1.0f + degacc[n]);  // 1 = self-loop
}

// ---------------- MFMA GEMM: H' = (dinv*act(X)) @ W, fp8 e4m3 --------------
// 64 rows x 128 cols per block, 4 waves; A-fragments direct from global.
// Row scale dinv[row] folded into the A-fragment (1 load/lane, off the
// store path); epilogue is a plain fp8 store. Only W in LDS -> 4 blocks/CU.
__global__ __launch_bounds__(256, 4) void k_gemm5(const float* __restrict__ X,
                                                  const ushort* __restrict__ Xb,
                                                  const ushort* __restrict__ Wt,
                                                  const float* __restrict__ stats,
                                                  const float* __restrict__ gamma,
                                                  const float* __restrict__ beta,
                                                  const float* __restrict__ dinv,
                                                  int applyBN,
                                                  unsigned char* __restrict__ H) {
    __shared__ ushort ws[128 * 128];   // 32KB [n][k] bf16, swizzled
    __shared__ float scs[DD], shs[DD];
    const int tid = threadIdx.x;

    for (int c = tid; c < 2048; c += 256) {
        int n = c >> 4, k8 = (c & 15) * 8;
        uint4 w = *(const uint4*)&Wt[n * DD + k8];
        int idx = n * 128 + (((k8 * 2) ^ ((n & 7) << 4)) >> 1);
        *(uint4*)&ws[idx] = w;
    }
    if (applyBN && tid < DD) {
        float mu = stats[tid] * (1.0f / NN);
        float var = stats[DD + tid] * (1.0f / NN) - mu * mu;
        float inv = rsqrtf(var + EPSBN);
        float s = gamma[tid] * inv;
        scs[tid] = s;
        shs[tid] = beta[tid] - mu * s;
    }
    __syncthreads();

    const int wid = tid >> 6, lane = tid & 63;
    const int lrow = lane & 15, lk = lane >> 4;
    const int gr_a = blockIdx.x * 64 + wid * 16 + lrow;  // A row for this lane
    const float dva = (gr_a < NN) ? dinv[gr_a] : 0.f;    // row scale (A side)

    float4v acc[8];
#pragma unroll
    for (int i = 0; i < 8; ++i) acc[i] = (float4v){0.f, 0.f, 0.f, 0.f};

#pragma unroll
    for (int ks = 0; ks < 4; ++ks) {
        const int k8 = ks * 32 + lk * 8;   // this lane's 8 k-elements
        float v[8];
        if (applyBN) {
            uint4 g = (gr_a < NN) ? *(const uint4*)&Xb[(size_t)gr_a * DD + k8]
                                  : make_uint4(0u, 0u, 0u, 0u);
            v[0] = __uint_as_float(g.x << 16);
            v[1] = __uint_as_float(g.x & 0xffff0000u);
            v[2] = __uint_as_float(g.y << 16);
            v[3] = __uint_as_float(g.y & 0xffff0000u);
            v[4] = __uint_as_float(g.z << 16);
            v[5] = __uint_as_float(g.z & 0xffff0000u);
            v[6] = __uint_as_float(g.w << 16);
            v[7] = __uint_as_float(g.w & 0xffff0000u);
#pragma unroll
            for (int i = 0; i < 8; ++i)
                v[i] = dva * fmaxf(fmaf(v[i], scs[k8 + i], shs[k8 + i]), 0.f);
        } else {
            if (gr_a < NN) {
                float4 a0 = *(const float4*)&X[(size_t)gr_a * DD + k8];
                float4 a1 = *(const float4*)&X[(size_t)gr_a * DD + k8 + 4];
                v[0] = a0.x; v[1] = a0.y; v[2] = a0.z; v[3] = a0.w;
                v[4] = a1.x; v[5] = a1.y; v[6] = a1.z; v[7] = a1.w;
            } else {
#pragma unroll
                for (int i = 0; i < 8; ++i) v[i] = 0.f;
            }
#pragma unroll
            for (int i = 0; i < 8; ++i) v[i] *= dva;
        }
        uint4 ap;
        ap.x = (uint)f2bf(v[0]) | ((uint)f2bf(v[1]) << 16);
        ap.y = (uint)f2bf(v[2]) | ((uint)f2bf(v[3]) << 16);
        ap.z = (uint)f2bf(v[4]) | ((uint)f2bf(v[5]) << 16);
        ap.w = (uint)f2bf(v[6]) | ((uint)f2bf(v[7]) << 16);
        short8v a = *(short8v*)&ap;

        const int kbyte = ks * 64 + lk * 16;
#pragma unroll
        for (int ng = 0; ng < 8; ++ng) {
            int n = ng * 16 + lrow;
            short8v b = *(const short8v*)&ws[n * 128 + ((kbyte ^ ((n & 7) << 4)) >> 1)];
            acc[ng] = __builtin_amdgcn_mfma_f32_16x16x32_bf16(a, b, acc[ng], 0, 0, 0);
        }
    }

    // C/D layout: col = lane&15, row = (lane>>4)*4 + reg  [m89]
    const int rbase = blockIdx.x * 64 + wid * 16 + lk * 4;
#pragma unroll
    for (int ng = 0; ng < 8; ++ng) {
        int col = ng * 16 + lrow;
#pragma unroll
        for (int j = 0; j < 4; ++j) {
            int gr = rbase + j;
            if (gr < NN)
                H[(size_t)gr * DD + col] = (unsigned char)f2fp8(acc[ng][j]);
        }
    }
}

// ---------------- aggregation + fused BN stats ----------------------------
// H is pre-scaled by dinv[row]: edge weight = raw ew; self-loop seed = 1.0;
// final *dv completes dinv[dst]*ew*dinv[src] and dv^2 for the self loop.
__global__ __launch_bounds__(256) void k_agg3(const int2* __restrict__ csr,
                                              const int* __restrict__ row_off,
                                              const float* __restrict__ dinv,
                                              const unsigned char* __restrict__ H,
                                              ushort* __restrict__ Ab,
                                              float* __restrict__ partial) {
    __shared__ float sbv[16][128];
    __shared__ float sbq[16][128];
    const int tid = threadIdx.x;
    int node = blockIdx.x * 16 + (tid >> 4);
    int h = tid & 15;
    int beg = row_off[node], end = row_off[node + 1];
    float dv = dinv[node];
    size_t cb = (size_t)node * DD + h * 8;   // byte index
    float acc[8] = {0.f, 0.f, 0.f, 0.f, 0.f, 0.f, 0.f, 0.f};
    {
        uint2 v = *(const uint2*)&H[cb];
        accf8(acc, v, 1.0f);  // H'[node] = dv*H[node]; final *dv gives dv^2*H
    }

    int j = beg;
    for (; j + 8 <= end; j += 8) {
        int2 e0 = csr[j], e1 = csr[j + 1], e2 = csr[j + 2], e3 = csr[j + 3];
        int2 e4 = csr[j + 4], e5 = csr[j + 5], e6 = csr[j + 6], e7 = csr[j + 7];
        uint2 g0 = *(const uint2*)&H[(size_t)e0.x * DD + h * 8];
        uint2 g1 = *(const uint2*)&H[(size_t)e1.x * DD + h * 8];
        uint2 g2 = *(const uint2*)&H[(size_t)e2.x * DD + h * 8];
        uint2 g3 = *(const uint2*)&H[(size_t)e3.x * DD + h * 8];
        uint2 g4 = *(const uint2*)&H[(size_t)e4.x * DD + h * 8];
        uint2 g5 = *(const uint2*)&H[(size_t)e5.x * DD + h * 8];
        uint2 g6 = *(const uint2*)&H[(size_t)e6.x * DD + h * 8];
        uint2 g7 = *(const uint2*)&H[(size_t)e7.x * DD + h * 8];
        accf8(acc, g0, __int_as_float(e0.y));
        accf8(acc, g1, __int_as_float(e1.y));
        accf8(acc, g2, __int_as_float(e2.y));
        accf8(acc, g3, __int_as_float(e3.y));
        accf8(acc, g4, __int_as_float(e4.y));
        accf8(acc, g5, __int_as_float(e5.y));
        accf8(acc, g6, __int_as_float(e6.y));
        accf8(acc, g7, __int_as_float(e7.y));
    }
    for (; j + 4 <= end; j += 4) {
        int2 e0 = csr[j], e1 = csr[j + 1], e2 = csr[j + 2], e3 = csr[j + 3];
        uint2 g0 = *(const uint2*)&H[(size_t)e0.x * DD + h * 8];
        uint2 g1 = *(const uint2*)&H[(size_t)e1.x * DD + h * 8];
        uint2 g2 = *(const uint2*)&H[(size_t)e2.x * DD + h * 8];
        uint2 g3 = *(const uint2*)&H[(size_t)e3.x * DD + h * 8];
        accf8(acc, g0, __int_as_float(e0.y));
        accf8(acc, g1, __int_as_float(e1.y));
        accf8(acc, g2, __int_as_float(e2.y));
        accf8(acc, g3, __int_as_float(e3.y));
    }
    for (; j < end; ++j) {
        int2 e = csr[j];
        uint2 g = *(const uint2*)&H[(size_t)e.x * DD + h * 8];
        accf8(acc, g, __int_as_float(e.y));
    }

#pragma unroll
    for (int i = 0; i < 8; ++i) acc[i] *= dv;

    uint4 st;
    st.x = (uint)f2bf(acc[0]) | ((uint)f2bf(acc[1]) << 16);
    st.y = (uint)f2bf(acc[2]) | ((uint)f2bf(acc[3]) << 16);
    st.z = (uint)f2bf(acc[4]) | ((uint)f2bf(acc[5]) << 16);
    st.w = (uint)f2bf(acc[6]) | ((uint)f2bf(acc[7]) << 16);
    *(uint4*)&Ab[cb] = st;

    int n = tid >> 4, c0 = h * 8;
#pragma unroll
    for (int i = 0; i < 8; ++i) {
        float a = acc[i];
        sbv[n][c0 + i] = a;
        sbq[n][c0 + i] = a * a;
    }
    __syncthreads();
    float s = 0.f;
    if (tid < 128) {
#pragma unroll
        for (int k = 0; k < 16; ++k) s += sbv[k][tid];
    } else {
        int c = tid - 128;
#pragma unroll
        for (int k = 0; k < 16; ++k) s += sbq[k][c];
    }
    partial[(size_t)blockIdx.x * 256 + tid] = s;
}

// ---------------- reduce partials -> stats (low-contention atomics) -------
__global__ __launch_bounds__(256) void k_bn_red(const float* __restrict__ partial,
                                                float* __restrict__ stats) {
    int r0 = blockIdx.x * 25;
    int r1 = min(r0 + 25, NAGG);
    int t = threadIdx.x;
    float s = 0.f;
    for (int r = r0; r < r1; ++r) s += partial[(size_t)r * 256 + t];
    atomAddF(&stats[t], s);
}

// ---------------- pooling (fused final BN+ReLU), vectorized ---------------
__global__ __launch_bounds__(256) void k_pool(const ushort* __restrict__ Ab,
                                              const int* __restrict__ batch,
                                              const float* __restrict__ stats,
                                              const float* __restrict__ gamma,
                                              const float* __restrict__ beta,
                                              float* __restrict__ out) {
    __shared__ int bsh[512];
    __shared__ float scs[DD], shs[DD];
    const int tid = threadIdx.x;
    const int lane = tid & 15, rg = tid >> 4;
    const int c0 = lane * 8;
    const int v0 = blockIdx.x * 512;
    const int v1 = min(v0 + 512, NN);
    for (int i = tid; i < v1 - v0; i += 256) bsh[i] = batch[v0 + i];
    if (tid < DD) {
        float mu = stats[tid] * (1.0f / NN);
        float var = stats[DD + tid] * (1.0f / NN) - mu * mu;
        float inv = rsqrtf(var + EPSBN);
        float s = gamma[tid] * inv;
        scs[tid] = s;
        shs[tid] = beta[tid] - mu * s;
    }
    __syncthreads();

    float s[8], t[8];
#pragma unroll
    for (int i = 0; i < 8; ++i) {
        s[i] = scs[c0 + i];
        t[i] = shs[c0 + i];
    }
    float acc[8] = {0.f, 0.f, 0.f, 0.f, 0.f, 0.f, 0.f, 0.f};
    int g = -1;
    for (int v = v0 + rg; v < v1; v += 16) {
        int bg = bsh[v - v0];
        if (bg != g) {
            if (g >= 0) {
                float* op = &out[(size_t)g * DD + c0];
#pragma unroll
                for (int i = 0; i < 8; ++i) atomAddF(op + i, acc[i]);
            }
            g = bg;
#pragma unroll
            for (int i = 0; i < 8; ++i) acc[i] = 0.f;
        }
        uint4 a = *(const uint4*)&Ab[(size_t)v * DD + c0];
        float x0 = __uint_as_float(a.x << 16);
        float x1 = __uint_as_float(a.x & 0xffff0000u);
        float x2 = __uint_as_float(a.y << 16);
        float x3 = __uint_as_float(a.y & 0xffff0000u);
        float x4 = __uint_as_float(a.z << 16);
        float x5 = __uint_as_float(a.z & 0xffff0000u);
        float x6 = __uint_as_float(a.w << 16);
        float x7 = __uint_as_float(a.w & 0xffff0000u);
        acc[0] += fmaxf(fmaf(x0, s[0], t[0]), 0.f);
        acc[1] += fmaxf(fmaf(x1, s[1], t[1]), 0.f);
        acc[2] += fmaxf(fmaf(x2, s[2], t[2]), 0.f);
        acc[3] += fmaxf(fmaf(x3, s[3], t[3]), 0.f);
        acc[4] += fmaxf(fmaf(x4, s[4], t[4]), 0.f);
        acc[5] += fmaxf(fmaf(x5, s[5], t[5]), 0.f);
        acc[6] += fmaxf(fmaf(x6, s[6], t[6]), 0.f);
        acc[7] += fmaxf(fmaf(x7, s[7], t[7]), 0.f);
    }
    if (g >= 0) {
        float* op = &out[(size_t)g * DD + c0];
#pragma unroll
        for (int i = 0; i < 8; ++i) atomAddF(op + i, acc[i]);
    }
}

extern "C" void kernel_launch(void* const* d_in, const int* in_sizes, int n_in,
                              void* d_out, int out_size, void* d_ws, size_t ws_size,
                              hipStream_t stream) {
    const float* x     = (const float*)d_in[0];
    const int*   ei    = (const int*)d_in[1];
    const float* ew    = (const float*)d_in[2];
    const int*   batch = (const int*)d_in[3];
    const float* W     = (const float*)d_in[4];
    // d_in[5] = b — cancels exactly in training-mode BatchNorm, unused
    const float* gamma = (const float*)d_in[6];
    const float* beta  = (const float*)d_in[7];
    float* out = (float*)d_out;

    float* wsp   = (float*)d_ws;
    float* dinv  = wsp;                            // N
    float* stats = dinv + NN;                      // 768
    ushort* Wt   = (ushort*)(stats + 768);         // 3 x D x D bf16
    unsigned char* H = (unsigned char*)(Wt + (size_t)NL * DD * DD);  // N*D fp8
    ushort* Ab   = (ushort*)(H + (size_t)NN * DD); // N*D bf16
    int2*  srcw  = (int2*)(Ab + (size_t)NN * DD);  // E packed records
    float* partial = (float*)(srcw + NE);          // NAGG x 256
    int*   row_off = (int*)(partial + (size_t)NAGG * 256);  // N+4
    int*   hist  = row_off + NN + 4;               // NSCAT x NBUCK
    int*   prefix = hist + NSCAT * NBUCK;          // NSCAT x NBUCK
    int*   boff  = prefix + NSCAT * NBUCK;         // NBUCK+4 (padded)
    int2*  csr   = (int2*)(boff + NBUCK + 4);      // E * 8B
    // total ≈ 71 MiB

    // build chain: per-block histograms (+init) -> scan -> scatter -> sort
    k_bcnt2<<<NSCAT, 256, 0, stream>>>(ei, W, Wt, out, stats, hist);
    k_bscan2<<<1, 256, 0, stream>>>(hist, prefix, boff);
    k_bscatter2<<<NSCAT, 256, 0, stream>>>(ei, ew, prefix, boff, srcw);
    k_bsort<<<NBUCK, 256, 0, stream>>>(srcw, boff, row_off, csr, dinv);

    for (int l = 0; l < NL; ++l) {
        const float* st_prev = stats + (l - 1) * 256;   // unused when l==0
        const float* ga_prev = gamma + (size_t)(l > 0 ? l - 1 : 0) * DD;
        const float* be_prev = beta + (size_t)(l > 0 ? l - 1 : 0) * DD;
        k_gemm5<<<(NN + 63) / 64, 256, 0, stream>>>(
            x, Ab, Wt + (size_t)l * DD * DD, l > 0 ? st_prev : stats,
            ga_prev, be_prev, dinv, l > 0 ? 1 : 0, H);
        k_agg3<<<NAGG, 256, 0, stream>>>(csr, row_off, dinv, H, Ab, partial);
        k_bn_red<<<(NAGG + 24) / 25, 256, 0, stream>>>(partial, stats + l * 256);
    }

    k_pool<<<NBUCK, 256, 0, stream>>>(Ab, batch, stats + 2 * 256,
                                      gamma + 2 * DD, beta + 2 * DD, out);
}